// Round 4
// baseline (340.787 us; speedup 1.0000x reference)
//
#include <hip/hip_runtime.h>

#define NODE_IN 64
#define EDGE_IN 32
#define GLOBAL_IN 32
#define HID 128
#define EOUT 32

typedef float f32x4 __attribute__((ext_vector_type(4)));
typedef float f32x2 __attribute__((ext_vector_type(2)));
typedef short s16x8 __attribute__((ext_vector_type(8)));
typedef unsigned short u16x8 __attribute__((ext_vector_type(8)));

// native bf16 cast (RNE); pairs fuse into v_cvt_pk_bf16_f32
__device__ __forceinline__ unsigned short f2bf(float f) {
  __bf16 h = (__bf16)f;
  return __builtin_bit_cast(unsigned short, h);
}

// load 8 contiguous f32, convert to an s16x8 bf16 MFMA fragment in-register
__device__ __forceinline__ s16x8 ld_frag(const float* __restrict__ p) {
  const f32x4 a = *(const f32x4*)p;
  const f32x4 b = *(const f32x4*)(p + 4);
  u16x8 v = { f2bf(a[0]), f2bf(a[1]), f2bf(a[2]), f2bf(a[3]),
              f2bf(b[0]), f2bf(b[1]), f2bf(b[2]), f2bf(b[3]) };
  return __builtin_bit_cast(s16x8, v);
}

// Block = 4 waves, tile = 64 edges. NO X staging in LDS: the 16x16x32 A-frag
// (lane -> X[r16][8g+j]) is 8 contiguous f32 in the source rows, so each wave
// direct-loads + converts its A-frags from global (4x L2 re-read across the
// n-split waves; HBM unchanged). Latency is hidden by counted-vmcnt pipelining
// + wave stagger instead of lockstep barriers. Only H crosses waves:
// double-buffered H in LDS -> exactly ONE __syncthreads per tile (WAR on the
// H buffer is covered by the next tile's barrier).
__global__ __launch_bounds__(256) void edge_mlp(
    const float* __restrict__ srcp, const float* __restrict__ dstp,
    const float* __restrict__ eap, const float* __restrict__ up,
    const int* __restrict__ ebp, const float* __restrict__ W1,
    const float* __restrict__ b1, const float* __restrict__ W2,
    const float* __restrict__ b2, float* __restrict__ outp,
    int E, int ntiles)
{
  __shared__ __align__(16) unsigned short Hb[2][64 * 136];  // 34816 B

  const int t = threadIdx.x;
  const int wid = t >> 6;
  const int lane = t & 63;
  const int g = lane >> 4;
  const int r16 = lane & 15;

  // ---- weight fragments (once per block; L2-resident source) ----
  // layer-1 B-frag, permuted cols: lane-col r16 of MFMA (wid,nt) -> H col 32w+2r+nt
  s16x8 w1f[6][2];
#pragma unroll
  for (int kk = 0; kk < 6; ++kk) {
#pragma unroll
    for (int nt = 0; nt < 2; ++nt) {
      s16x8 v;
#pragma unroll
      for (int j = 0; j < 8; ++j)
        v[j] = (short)f2bf(W1[(32*kk + 8*g + j)*HID + 32*wid + 2*r16 + nt]);
      w1f[kk][nt] = v;
    }
  }
  // layer-2 B-frag, permuted cols: lane-col r16 -> out col 2r+nt
  s16x8 w2f[4][2];
#pragma unroll
  for (int kk = 0; kk < 4; ++kk) {
#pragma unroll
    for (int nt = 0; nt < 2; ++nt) {
      s16x8 v;
#pragma unroll
      for (int j = 0; j < 8; ++j)
        v[j] = (short)f2bf(W2[(32*kk + 8*g + j)*EOUT + 2*r16 + nt]);
      w2f[kk][nt] = v;
    }
  }
  const float b1v0 = b1[32*wid + 2*r16];
  const float b1v1 = b1[32*wid + 2*r16 + 1];
  const float b2v0 = b2[2*r16];
  const float b2v1 = b2[2*r16 + 1];
  const int Em1 = E - 1;

  int buf = 0;
  for (int tile = blockIdx.x; tile < ntiles; tile += gridDim.x, buf ^= 1) {
    const int mbase = tile * 64;

    // batch indices first (breaks the ebp->u dependent chain early)
    int bb[4];
#pragma unroll
    for (int mi = 0; mi < 4; ++mi)
      bb[mi] = ebp[min(mbase + 16*mi + r16, Em1)];

    // ---- layer 1: A-frags straight from global, 4 m-tiles x 2 n-tiles ----
    f32x4 acc[4][2];
    {
      const f32x4 z = {0.f, 0.f, 0.f, 0.f};
#pragma unroll
      for (int mi = 0; mi < 4; ++mi) { acc[mi][0] = z; acc[mi][1] = z; }
    }
#pragma unroll
    for (int mi = 0; mi < 4; ++mi) {
      const int row = min(mbase + 16*mi + r16, Em1);
      const float* ps = srcp + (size_t)row*NODE_IN + 8*g;
      const float* pd = dstp + (size_t)row*NODE_IN + 8*g;
      const s16x8 f0 = ld_frag(ps);
      const s16x8 f1 = ld_frag(ps + 32);
      const s16x8 f2 = ld_frag(pd);
      const s16x8 f3 = ld_frag(pd + 32);
      const s16x8 f4 = ld_frag(eap + (size_t)row*EDGE_IN + 8*g);
      const s16x8 f5 = ld_frag(up + (size_t)bb[mi]*GLOBAL_IN + 8*g);
      acc[mi][0] = __builtin_amdgcn_mfma_f32_16x16x32_bf16(f0, w1f[0][0], acc[mi][0], 0, 0, 0);
      acc[mi][1] = __builtin_amdgcn_mfma_f32_16x16x32_bf16(f0, w1f[0][1], acc[mi][1], 0, 0, 0);
      acc[mi][0] = __builtin_amdgcn_mfma_f32_16x16x32_bf16(f1, w1f[1][0], acc[mi][0], 0, 0, 0);
      acc[mi][1] = __builtin_amdgcn_mfma_f32_16x16x32_bf16(f1, w1f[1][1], acc[mi][1], 0, 0, 0);
      acc[mi][0] = __builtin_amdgcn_mfma_f32_16x16x32_bf16(f2, w1f[2][0], acc[mi][0], 0, 0, 0);
      acc[mi][1] = __builtin_amdgcn_mfma_f32_16x16x32_bf16(f2, w1f[2][1], acc[mi][1], 0, 0, 0);
      acc[mi][0] = __builtin_amdgcn_mfma_f32_16x16x32_bf16(f3, w1f[3][0], acc[mi][0], 0, 0, 0);
      acc[mi][1] = __builtin_amdgcn_mfma_f32_16x16x32_bf16(f3, w1f[3][1], acc[mi][1], 0, 0, 0);
      acc[mi][0] = __builtin_amdgcn_mfma_f32_16x16x32_bf16(f4, w1f[4][0], acc[mi][0], 0, 0, 0);
      acc[mi][1] = __builtin_amdgcn_mfma_f32_16x16x32_bf16(f4, w1f[4][1], acc[mi][1], 0, 0, 0);
      acc[mi][0] = __builtin_amdgcn_mfma_f32_16x16x32_bf16(f5, w1f[5][0], acc[mi][0], 0, 0, 0);
      acc[mi][1] = __builtin_amdgcn_mfma_f32_16x16x32_bf16(f5, w1f[5][1], acc[mi][1], 0, 0, 0);
    }

    // ---- epilogue: +b1, relu, packed dword writes into Hb[buf] ----
    unsigned short* __restrict__ H = &Hb[buf][0];
#pragma unroll
    for (int mi = 0; mi < 4; ++mi) {
#pragma unroll
      for (int j = 0; j < 4; ++j) {
        const float h0 = fmaxf(acc[mi][0][j] + b1v0, 0.f);
        const float h1 = fmaxf(acc[mi][1][j] + b1v1, 0.f);
        const unsigned int pk = (unsigned int)f2bf(h0) |
                                ((unsigned int)f2bf(h1) << 16);
        *(unsigned int*)&H[(16*mi + 4*g + j)*136 + 32*wid + 2*r16] = pk;
      }
    }
    __syncthreads();                           // the only barrier per tile

    // ---- layer 2: 16 rows/wave, K=128 ----
    f32x4 acc2[2];
    {
      const f32x4 z = {0.f, 0.f, 0.f, 0.f};
      acc2[0] = z; acc2[1] = z;
    }
#pragma unroll
    for (int kk = 0; kk < 4; ++kk) {
      const s16x8 a = *(const s16x8*)&H[(16*wid + r16)*136 + 32*kk + 8*g];
      acc2[0] = __builtin_amdgcn_mfma_f32_16x16x32_bf16(a, w2f[kk][0], acc2[0], 0, 0, 0);
      acc2[1] = __builtin_amdgcn_mfma_f32_16x16x32_bf16(a, w2f[kk][1], acc2[1], 0, 0, 0);
    }
#pragma unroll
    for (int j = 0; j < 4; ++j) {
      const int m = mbase + 16*wid + 4*g + j;
      if (m < E) {
        f32x2 o = { acc2[0][j] + b2v0, acc2[1][j] + b2v1 };
        *(f32x2*)(outp + (size_t)m*EOUT + 2*r16) = o;
      }
    }
    // no trailing barrier: next tile writes Hb[buf^1]; reuse of THIS buf is
    // separated by the next tile's __syncthreads (all waves' reads precede it).
  }
}

extern "C" void kernel_launch(void* const* d_in, const int* in_sizes, int n_in,
                              void* d_out, int out_size, void* d_ws, size_t ws_size,
                              hipStream_t stream) {
  const float* srcp = (const float*)d_in[0];
  const float* dstp = (const float*)d_in[1];
  const float* eap  = (const float*)d_in[2];
  const float* up   = (const float*)d_in[3];
  const int*   ebp  = (const int*)d_in[4];
  const float* W1   = (const float*)d_in[5];
  const float* b1   = (const float*)d_in[6];
  const float* W2   = (const float*)d_in[7];
  const float* b2   = (const float*)d_in[8];
  float* outp = (float*)d_out;

  const int E = in_sizes[0] / NODE_IN;
  const int ntiles = (E + 63) / 64;
  const int grid = ntiles < 2048 ? ntiles : 2048;

  edge_mlp<<<grid, 256, 0, stream>>>(srcp, dstp, eap, up, ebp, W1, b1, W2, b2,
                                     outp, E, ntiles);
}

// Round 5
// 155.073 us; speedup vs baseline: 2.1976x; 2.1976x over previous
//
#include <hip/hip_runtime.h>

#define NODE_IN 64
#define EDGE_IN 32
#define GLOBAL_IN 32
#define HID 128
#define EOUT 32

typedef float f32x4 __attribute__((ext_vector_type(4)));
typedef float f32x2 __attribute__((ext_vector_type(2)));
typedef short s16x8 __attribute__((ext_vector_type(8)));
typedef unsigned short u16x8 __attribute__((ext_vector_type(8)));

// native bf16 cast (RNE); pairs fuse into v_cvt_pk_bf16_f32
__device__ __forceinline__ unsigned short f2bf(float f) {
  __bf16 h = (__bf16)f;
  return __builtin_bit_cast(unsigned short, h);
}

__device__ __forceinline__ u16x8 cvt8(f32x4 a, f32x4 b) {
  u16x8 v = { f2bf(a[0]), f2bf(a[1]), f2bf(a[2]), f2bf(a[3]),
              f2bf(b[0]), f2bf(b[1]), f2bf(b[2]), f2bf(b[3]) };
  return v;
}

// lgkmcnt-only barrier: does NOT drain vmcnt, so prefetched global loads stay
// in flight across it (T4). __syncthreads would emit s_waitcnt vmcnt(0) and
// serialize the pipeline (rounds 1/3: 164us lockstep).
__device__ __forceinline__ void bar_lds() {
  asm volatile("s_waitcnt lgkmcnt(0)" ::: "memory");
  __builtin_amdgcn_s_barrier();
  asm volatile("" ::: "memory");
}

// Block = 4 waves, tile = 64 edges. Round-3 cooperative structure (X bf16 in
// LDS, H bf16 in LDS) + register prefetch pipeline: tile t+1's 12 f32x4 global
// loads are issued in tile t's tail (ebp prefetched 2 tiles deep to cover the
// ebp->u dependent gather), cvt+ds_write happen write-late, and barriers are
// lgkmcnt-only so the loads overlap all of tile t+1's compute.
__global__ __launch_bounds__(256) void edge_mlp(
    const float* __restrict__ srcp, const float* __restrict__ dstp,
    const float* __restrict__ eap, const float* __restrict__ up,
    const int* __restrict__ ebp, const float* __restrict__ W1,
    const float* __restrict__ b1, const float* __restrict__ W2,
    const float* __restrict__ b2, float* __restrict__ outp,
    int E, int ntiles)
{
  __shared__ __align__(16) unsigned short SMX[64 * 200];  // X bf16, 25.6 KB
  __shared__ __align__(16) unsigned short SMH[64 * 136];  // H bf16, 17.4 KB

  const int t = threadIdx.x;
  const int wid = t >> 6;
  const int lane = t & 63;
  const int g = lane >> 4;
  const int r16 = lane & 15;
  const int rA = t >> 3;           // src/dst staging rows rA and rA+32
  const int cA = (t & 7) * 8;
  const int rC = t >> 2;           // ea/u staging row
  const int cC = (t & 3) * 8;
  const int Em1 = E - 1;

  // ---- weight fragments (once per block; L2-resident source) ----
  s16x8 w1f[6][2];
#pragma unroll
  for (int kk = 0; kk < 6; ++kk) {
#pragma unroll
    for (int nt = 0; nt < 2; ++nt) {
      s16x8 v;
#pragma unroll
      for (int j = 0; j < 8; ++j)
        v[j] = (short)f2bf(W1[(32*kk + 8*g + j)*HID + 32*wid + 2*r16 + nt]);
      w1f[kk][nt] = v;
    }
  }
  s16x8 w2f[4][2];
#pragma unroll
  for (int kk = 0; kk < 4; ++kk) {
#pragma unroll
    for (int nt = 0; nt < 2; ++nt) {
      s16x8 v;
#pragma unroll
      for (int j = 0; j < 8; ++j)
        v[j] = (short)f2bf(W2[(32*kk + 8*g + j)*EOUT + 2*r16 + nt]);
      w2f[kk][nt] = v;
    }
  }
  const float b1v0 = b1[32*wid + 2*r16];
  const float b1v1 = b1[32*wid + 2*r16 + 1];
  const float b2v0 = b2[2*r16];
  const float b2v1 = b2[2*r16 + 1];

  // ---- prefetch pipeline state: 12 f32x4 for one X-tile slice ----
  f32x4 P[12];
  auto issue_sde = [&](int mb) {   // src, dest, edge_attr for tile at mb
    const int r0 = min(mb + rA, Em1);
    const int r1 = min(mb + 32 + rA, Em1);
    const int r2 = min(mb + rC, Em1);
    const float* s0 = srcp + (size_t)r0 * NODE_IN + cA;
    const float* s1 = srcp + (size_t)r1 * NODE_IN + cA;
    const float* d0 = dstp + (size_t)r0 * NODE_IN + cA;
    const float* d1 = dstp + (size_t)r1 * NODE_IN + cA;
    const float* e0 = eap  + (size_t)r2 * EDGE_IN + cC;
    P[0] = *(const f32x4*)s0;  P[1] = *(const f32x4*)(s0 + 4);
    P[2] = *(const f32x4*)s1;  P[3] = *(const f32x4*)(s1 + 4);
    P[4] = *(const f32x4*)d0;  P[5] = *(const f32x4*)(d0 + 4);
    P[6] = *(const f32x4*)d1;  P[7] = *(const f32x4*)(d1 + 4);
    P[8] = *(const f32x4*)e0;  P[9] = *(const f32x4*)(e0 + 4);
  };
  auto issue_u = [&](int bb) {     // u-gather (bb = arrived ebp value)
    const float* uu = up + (size_t)bb * GLOBAL_IN + cC;
    P[10] = *(const f32x4*)uu;  P[11] = *(const f32x4*)(uu + 4);
  };
  auto write_x = [&]() {           // cvt + ds_write (consumes P)
    *(u16x8*)&SMX[rA*200 + cA]           = cvt8(P[0], P[1]);
    *(u16x8*)&SMX[(rA+32)*200 + cA]      = cvt8(P[2], P[3]);
    *(u16x8*)&SMX[rA*200 + 64 + cA]      = cvt8(P[4], P[5]);
    *(u16x8*)&SMX[(rA+32)*200 + 64 + cA] = cvt8(P[6], P[7]);
    *(u16x8*)&SMX[rC*200 + 128 + cC]     = cvt8(P[8], P[9]);
    *(u16x8*)&SMX[rC*200 + 160 + cC]     = cvt8(P[10], P[11]);
  };

  int tile = blockIdx.x;
  const int TS = gridDim.x;

  // ---- prologue: fill the pipe ----
  {
    const int mb0 = tile * 64;
    const int eb0 = ebp[min(mb0 + rC, Em1)];
    issue_sde(mb0);
    issue_u(eb0);
    write_x();                                    // tile0 staged
    const int mb1 = (tile + TS) * 64;
    const int eb1 = ebp[min(mb1 + rC, Em1)];
    issue_sde(mb1);
    issue_u(eb1);                                 // tile0+TS in flight
  }
  int ebv = ebp[min((tile + 2*TS) * 64 + rC, Em1)];  // ebp 2 tiles deep
  bar_lds();                                      // X(tile0) ready

  for (; tile < ntiles; tile += TS) {
    const int mbase = tile * 64;

    // ---- layer 1: 4 m-tiles x 2 n-tiles, K=192, from SMX ----
    f32x4 acc[4][2];
    {
      const f32x4 z = {0.f, 0.f, 0.f, 0.f};
#pragma unroll
      for (int mi = 0; mi < 4; ++mi) { acc[mi][0] = z; acc[mi][1] = z; }
    }
#pragma unroll
    for (int kk = 0; kk < 6; ++kk) {
#pragma unroll
      for (int mi = 0; mi < 4; ++mi) {
        const s16x8 a = *(const s16x8*)&SMX[(16*mi + r16)*200 + 32*kk + 8*g];
        acc[mi][0] = __builtin_amdgcn_mfma_f32_16x16x32_bf16(a, w1f[kk][0], acc[mi][0], 0, 0, 0);
        acc[mi][1] = __builtin_amdgcn_mfma_f32_16x16x32_bf16(a, w1f[kk][1], acc[mi][1], 0, 0, 0);
      }
    }

    // ---- epilogue: +b1, relu, packed dword writes into SMH ----
#pragma unroll
    for (int mi = 0; mi < 4; ++mi) {
#pragma unroll
      for (int j = 0; j < 4; ++j) {
        const float h0 = fmaxf(acc[mi][0][j] + b1v0, 0.f);
        const float h1 = fmaxf(acc[mi][1][j] + b1v1, 0.f);
        const unsigned int pk = (unsigned int)f2bf(h0) |
                                ((unsigned int)f2bf(h1) << 16);
        *(unsigned int*)&SMH[(16*mi + 4*g + j)*136 + 32*wid + 2*r16] = pk;
      }
    }
    bar_lds();                  // B1: H ready; also gates X-WAR (L1 reads done)

    // ---- layer 2: 16 rows/wave, K=128 ----
    f32x4 acc2[2];
    {
      const f32x4 z = {0.f, 0.f, 0.f, 0.f};
      acc2[0] = z; acc2[1] = z;
    }
#pragma unroll
    for (int kk = 0; kk < 4; ++kk) {
      const s16x8 a = *(const s16x8*)&SMH[(16*wid + r16)*136 + 32*kk + 8*g];
      acc2[0] = __builtin_amdgcn_mfma_f32_16x16x32_bf16(a, w2f[kk][0], acc2[0], 0, 0, 0);
      acc2[1] = __builtin_amdgcn_mfma_f32_16x16x32_bf16(a, w2f[kk][1], acc2[1], 0, 0, 0);
    }
#pragma unroll
    for (int j = 0; j < 4; ++j) {
      const int m = mbase + 16*wid + 4*g + j;
      if (m < E) {
        f32x2 o = { acc2[0][j] + b2v0, acc2[1][j] + b2v1 };
        *(f32x2*)(outp + (size_t)m*EOUT + 2*r16) = o;
      }
    }

    // ---- tail: stage tile+TS (write-late), issue tile+2TS (issue-early) ----
    write_x();                                   // counted vmcnt wait on P only
    issue_sde((tile + 2*TS) * 64);
    issue_u(ebv);                                // ebv arrived (issued last tail)
    ebv = ebp[min((tile + 3*TS) * 64 + rC, Em1)];
    bar_lds();                  // B3: X(tile+TS) ready; gates H-WAR for next epi
  }
}

extern "C" void kernel_launch(void* const* d_in, const int* in_sizes, int n_in,
                              void* d_out, int out_size, void* d_ws, size_t ws_size,
                              hipStream_t stream) {
  const float* srcp = (const float*)d_in[0];
  const float* dstp = (const float*)d_in[1];
  const float* eap  = (const float*)d_in[2];
  const float* up   = (const float*)d_in[3];
  const int*   ebp  = (const int*)d_in[4];
  const float* W1   = (const float*)d_in[5];
  const float* b1   = (const float*)d_in[6];
  const float* W2   = (const float*)d_in[7];
  const float* b2   = (const float*)d_in[8];
  float* outp = (float*)d_out;

  const int E = in_sizes[0] / NODE_IN;
  const int ntiles = (E + 63) / 64;
  const int grid = ntiles < 2048 ? ntiles : 2048;

  edge_mlp<<<grid, 256, 0, stream>>>(srcp, dstp, eap, up, ebp, W1, b1, W2, b2,
                                     outp, E, ntiles);
}